// Round 5
// baseline (272.878 us; speedup 1.0000x reference)
//
#include <hip/hip_runtime.h>
#include <math.h>

typedef __attribute__((ext_vector_type(8))) short short8;
typedef __attribute__((ext_vector_type(8))) _Float16 half8;
typedef __attribute__((ext_vector_type(4))) float floatx4;

// ---- bf16 helpers (round-to-nearest-even) ----
__device__ inline float bflo(unsigned u) { return __uint_as_float(u << 16); }
__device__ inline float bfhi(unsigned u) { return __uint_as_float(u & 0xffff0000u); }
__device__ inline unsigned short f2bf(float x) {
    unsigned u = __float_as_uint(x);
    return (unsigned short)((u + 0x7fffu + ((u >> 16) & 1u)) >> 16);
}
__device__ inline unsigned f2bf2(float lo, float hi) {
    unsigned a = __float_as_uint(lo), b = __float_as_uint(hi);
    a = (a + 0x7fffu + ((a >> 16) & 1u)) >> 16;
    b = (b + 0x7fffu + ((b >> 16) & 1u)) & 0xffff0000u;
    return a | b;
}
__device__ inline unsigned short f2h(float x) {
    _Float16 h = (_Float16)x;
    return __builtin_bit_cast(unsigned short, h);
}

// stage a nr x 16 raw halo tile (bf16, 32ch) into LDS; OOB -> zeros (SAME pad)
__device__ __forceinline__ void stage_halo(unsigned short* raw, const unsigned short* pl,
                                           int t, int npx, int gi0, int gj0)
{
    if (t < npx) {
        int ri = t >> 4, rj = t & 15;
        int gi = gi0 + ri, gj = gj0 + rj;
        uint4 v0 = {0u,0u,0u,0u}, v1 = v0, v2 = v0, v3 = v0;
        if ((unsigned)gi < 64u && (unsigned)gj < 64u) {
            const uint4* src = (const uint4*)(pl + (((gi << 6) + gj) << 5));
            v0 = src[0]; v1 = src[1]; v2 = src[2]; v3 = src[3];
        }
        uint4* d = (uint4*)&raw[t * 32];
        d[0] = v0; d[1] = v1; d[2] = v2; d[3] = v3;
    }
}

// ---------------------------------------------------------------------------
// Hand-rolled grid barrier: monotonic device-scope counter, per-phase target.
// Counter zeroed by a hipMemsetAsync node before the kernel (ws is poisoned
// each iteration, so it cannot be initialized in-kernel without a race).
// All 512 blocks are provably co-resident (LDS 51.2KB -> <=3/CU; LB(256,2)
// -> VGPR<=256 -> >=2/CU; 2*256 >= 512), so the spin cannot deadlock.
// ---------------------------------------------------------------------------
__device__ __forceinline__ void grid_barrier(unsigned* bar, unsigned target)
{
    __syncthreads();   // each wave: s_waitcnt vmcnt(0) -> its stores are in L2
    if (threadIdx.x == 0) {
        __threadfence();   // agent-scope release: writeback for cross-XCD
        __hip_atomic_fetch_add(bar, 1u, __ATOMIC_RELEASE, __HIP_MEMORY_SCOPE_AGENT);
        while (__hip_atomic_load(bar, __ATOMIC_ACQUIRE, __HIP_MEMORY_SCOPE_AGENT) < target) {
            __builtin_amdgcn_s_sleep(8);
        }
        __threadfence();   // agent-scope acquire: invalidate stale lines
    }
    __syncthreads();
}

// ws layout (bytes):
//   qkv1b @ 0        : 2*18*4096*32*2 = 9437184  bf16 [b][g][px][32] (pre-dw)
//   attnO @ 9437184  : 2*4096*192*2 = 3145728    bf16 [b*px][c]
//   bar   @ 16777216 : 64 B grid-barrier counter (memset to 0 per launch)

// ---------------------------------------------------------------------------
// Phase 1: QKV 1x1 conv as bf16 MFMA GEMM, M=8192(px) N=576(oc) K=192.
// tile in [0,1152): m-tile = tile & 127, n-tile = tile >> 7
// ---------------------------------------------------------------------------
__device__ void gq_tile(char* smem, int tile, const float* x, const float* W1,
                        const float* b1, unsigned short* qkv)
{
    unsigned short* As = (unsigned short*)smem;           // [64][200]
    unsigned short* Bs = (unsigned short*)(smem + 25600); // [64][200]
    const int t = threadIdx.x;
    const int m0 = (tile & 127) * 64;
    const int n0 = (tile >> 7) * 64;
    const int w = t >> 6, lane = t & 63;
    const int b = m0 >> 12, px0 = m0 & 4095;
    // ---- A: transpose-convert 64px x 192c ----
    {
        const float* xb = x + ((size_t)(b * 192) << 12) + px0 + lane;
        const int cb = w * 48;
        #pragma unroll
        for (int r4 = 0; r4 < 12; ++r4) {
            float v0 = xb[(size_t)(cb + r4 * 4 + 0) << 12];
            float v1 = xb[(size_t)(cb + r4 * 4 + 1) << 12];
            float v2 = xb[(size_t)(cb + r4 * 4 + 2) << 12];
            float v3 = xb[(size_t)(cb + r4 * 4 + 3) << 12];
            *(uint2*)&As[lane * 200 + cb + r4 * 4] =
                make_uint2(f2bf2(v0, v1), f2bf2(v2, v3));
        }
    }
    // ---- B: convert W1 slice [n0..n0+63][192] ----
    #pragma unroll
    for (int pass = 0; pass < 12; ++pass) {
        int idx = pass * 256 + t;
        int row = idx / 48, ch = idx - row * 48;
        float4 wv = *(const float4*)&W1[(size_t)(n0 + row) * 192 + ch * 4];
        *(uint2*)&Bs[row * 200 + ch * 4] =
            make_uint2(f2bf2(wv.x, wv.y), f2bf2(wv.z, wv.w));
    }
    __syncthreads();
    const int lm = lane & 15, lq = lane >> 4;
    floatx4 acc[4] = {};
    #pragma unroll
    for (int ks = 0; ks < 6; ++ks) {
        short8 bf = *(const short8*)&Bs[(w * 16 + lm) * 200 + ks * 32 + lq * 8];
        #pragma unroll
        for (int mt = 0; mt < 4; ++mt) {
            short8 af = *(const short8*)&As[(mt * 16 + lm) * 200 + ks * 32 + lq * 8];
            acc[mt] = __builtin_amdgcn_mfma_f32_16x16x32_bf16(af, bf, acc[mt], 0, 0, 0);
        }
    }
    __syncthreads();
    const float bias = b1[n0 + w * 16 + lm];
    #pragma unroll
    for (int mt = 0; mt < 4; ++mt)
        #pragma unroll
        for (int r = 0; r < 4; ++r)
            As[(mt * 16 + lq * 4 + r) * 72 + w * 16 + lm] = f2bf(acc[mt][r] + bias);
    __syncthreads();
    #pragma unroll
    for (int pass = 0; pass < 2; ++pass) {
        int idx = pass * 256 + t;           // 64 m x 8 n-groups
        int m = idx >> 3, n8 = idx & 7;
        uint4 val = *(const uint4*)&As[m * 72 + n8 * 8];
        int oc = n0 + n8 * 8;
        int g = oc >> 5, d = oc & 31;
        *(uint4*)&qkv[((((size_t)(b * 18 + g) << 12) + px0 + m) << 5) + d] = val;
    }
    __syncthreads();    // As/Bs dead before next tile reuses smem
}

// ---------------------------------------------------------------------------
// Phase 2: MFMA neighborhood attention with fused depthwise 3x3 (LDS-staged
// halo). tile in [0,768): bx = tile & 63, hb = tile>>6, b = hb/6, head = hb%6.
// ---------------------------------------------------------------------------
__device__ void attn_tile(char* smem, int tile, const unsigned short* qkv,
    const float* W2, const float* b2, const float* temp, const float* rpb,
    unsigned short* attnO)
{
    char* lds = smem;
    unsigned short* Ks  = (unsigned short*)lds;            // [208][40] bf16
    unsigned short* Ps  = (unsigned short*)lds;            // [64][232] f16 (alias)
    unsigned short* raw = (unsigned short*)(lds + 16640);  // halo stage, <=10240 B
    unsigned short* Vts = (unsigned short*)(lds + 29696);  // [32][232] f16
    float* rpbs = (float*)(lds + 44544);                   // [169]
    float* dwW  = (float*)(lds + 45248);                   // [3][9][32] plane-major
    float* dwB  = (float*)(lds + 48704);                   // [3][32]

    const int t = threadIdx.x;
    const int hb = tile >> 6;
    const int b = hb / 6, head = hb - b * 6;
    const int bx = tile & 63;
    const int ti = bx >> 3, tj = bx & 7;
    const int i0 = ti * 8, j0 = tj * 8;
    const int r0 = min(max(i0 - 3, 0), 50), c0 = min(max(j0 - 3, 0), 50);
    const unsigned short* qpl = qkv + ((size_t)(b * 18 + head) << 17);
    const unsigned short* kpl = qkv + ((size_t)(b * 18 + 6 + head) << 17);
    const unsigned short* vpl = qkv + ((size_t)(b * 18 + 12 + head) << 17);

    // ---- stage dw weights/bias + rpb, zero Vts pad cols ----
    for (int idx = t; idx < 864; idx += 256) {
        int plane = idx / 288, rem = idx - plane * 288;
        dwW[idx] = W2[(plane * 192 + head * 32 + (rem & 31)) * 9 + (rem >> 5)];
    }
    if (t < 96) dwB[t] = b2[(t >> 5) * 192 + head * 32 + (t & 31)];
    if (t < 169) rpbs[t] = rpb[head * 169 + t];
    for (int idx = t; idx < 448; idx += 256) {
        int row = (idx * 2341) >> 15;
        int c = idx - row * 14;
        ((unsigned*)(Vts + row * 232))[98 + c] = 0u;
    }

    // ---- K plane: dw + l2norm via two half-tiles ----
    for (int h = 0; h < 2; ++h) {
        stage_halo(raw, kpl, t, 144, r0 - 1 + h * 7, c0 - 1);
        __syncthreads();
        for (int s = 0; s < 2; ++s) {
            int task = s * 256 + t;
            if (task < 392) {
                int px = task >> 2, oct = task & 3;
                int rl = (px * 2341) >> 15, cc = px - rl * 14;
                float a[8];
                #pragma unroll
                for (int e = 0; e < 8; ++e) a[e] = dwB[32 + oct * 8 + e];
                #pragma unroll
                for (int tap = 0; tap < 9; ++tap) {
                    uint4 u = *(const uint4*)&raw[((rl + tap / 3) * 16 + cc + tap % 3) * 32 + oct * 8];
                    const float* wt = &dwW[(9 + tap) * 32 + oct * 8];
                    unsigned uu[4] = {u.x, u.y, u.z, u.w};
                    #pragma unroll
                    for (int e = 0; e < 4; ++e) {
                        a[e * 2]     = fmaf(bflo(uu[e]), wt[e * 2],     a[e * 2]);
                        a[e * 2 + 1] = fmaf(bfhi(uu[e]), wt[e * 2 + 1], a[e * 2 + 1]);
                    }
                }
                float ss = 0.f;
                #pragma unroll
                for (int e = 0; e < 8; ++e) ss = fmaf(a[e], a[e], ss);
                ss += __shfl_xor(ss, 1);
                ss += __shfl_xor(ss, 2);
                float rinv = 1.0f / fmaxf(sqrtf(ss), 1e-12f);
                int pxk = (h * 7 + rl) * 14 + cc;
                uint4 p;
                p.x = f2bf2(a[0] * rinv, a[1] * rinv);
                p.y = f2bf2(a[2] * rinv, a[3] * rinv);
                p.z = f2bf2(a[4] * rinv, a[5] * rinv);
                p.w = f2bf2(a[6] * rinv, a[7] * rinv);
                *(uint4*)&Ks[pxk * 40 + oct * 8] = p;
            }
        }
        __syncthreads();
    }

    // ---- V plane: dw, transposed f16 writes, two half-tiles ----
    for (int h = 0; h < 2; ++h) {
        stage_halo(raw, vpl, t, 144, r0 - 1 + h * 7, c0 - 1);
        __syncthreads();
        for (int s = 0; s < 2; ++s) {
            int task = s * 256 + t;
            if (task < 392) {
                int px = task >> 2, oct = task & 3;
                int rl = (px * 2341) >> 15, cc = px - rl * 14;
                float a[8];
                #pragma unroll
                for (int e = 0; e < 8; ++e) a[e] = dwB[64 + oct * 8 + e];
                #pragma unroll
                for (int tap = 0; tap < 9; ++tap) {
                    uint4 u = *(const uint4*)&raw[((rl + tap / 3) * 16 + cc + tap % 3) * 32 + oct * 8];
                    const float* wt = &dwW[(18 + tap) * 32 + oct * 8];
                    unsigned uu[4] = {u.x, u.y, u.z, u.w};
                    #pragma unroll
                    for (int e = 0; e < 4; ++e) {
                        a[e * 2]     = fmaf(bflo(uu[e]), wt[e * 2],     a[e * 2]);
                        a[e * 2 + 1] = fmaf(bfhi(uu[e]), wt[e * 2 + 1], a[e * 2 + 1]);
                    }
                }
                int pxk = (h * 7 + rl) * 14 + cc;
                #pragma unroll
                for (int e = 0; e < 8; ++e)
                    Vts[(oct * 8 + e) * 232 + pxk] = f2h(a[e]);
            }
        }
        __syncthreads();
    }

    // ---- Q plane: stage 10x16 halo, per-lane dw + l2norm ----
    stage_halo(raw, qpl, t, 160, i0 - 1, c0 - 1);
    __syncthreads();
    const int w = t >> 6, lane = t & 63;
    const int lm = lane & 15, lq = lane >> 4;
    const int px = w * 16 + lm;
    const int i = i0 + (px >> 3), j = j0 + (px & 7);
    const int qrow = px >> 3, qcol = (px & 7) + (j0 - c0);
    float qf[8];
    #pragma unroll
    for (int e = 0; e < 8; ++e) qf[e] = dwB[lq * 8 + e];
    #pragma unroll
    for (int tap = 0; tap < 9; ++tap) {
        uint4 u = *(const uint4*)&raw[((qrow + tap / 3) * 16 + qcol + tap % 3) * 32 + lq * 8];
        const float* wt = &dwW[tap * 32 + lq * 8];
        unsigned uu[4] = {u.x, u.y, u.z, u.w};
        #pragma unroll
        for (int e = 0; e < 4; ++e) {
            qf[e * 2]     = fmaf(bflo(uu[e]), wt[e * 2],     qf[e * 2]);
            qf[e * 2 + 1] = fmaf(bfhi(uu[e]), wt[e * 2 + 1], qf[e * 2 + 1]);
        }
    }
    float qs = 0.f;
    #pragma unroll
    for (int e = 0; e < 8; ++e) qs = fmaf(qf[e], qf[e], qs);
    qs += __shfl_xor(qs, 16);
    qs += __shfl_xor(qs, 32);
    float qinv = 1.0f / fmaxf(sqrtf(qs), 1e-12f);
    short8 bq;
    #pragma unroll
    for (int e = 0; e < 8; ++e) bq[e] = (short)f2bf(qf[e] * qinv);
    __syncthreads();

    // ---- QK^T: S^T[nbr][px], 13 n-tiles of 16 nbrs ----
    floatx4 acc[13];
    #pragma unroll
    for (int mt = 0; mt < 13; ++mt) {
        short8 ak = *(const short8*)&Ks[(mt * 16 + lm) * 40 + lq * 8];
        floatx4 z = {0.f, 0.f, 0.f, 0.f};
        acc[mt] = __builtin_amdgcn_mfma_f32_16x16x32_bf16(ak, bq, z, 0, 0, 0);
    }
    __syncthreads();                        // Ks dead; Ps may overwrite

    // ---- mask + bias + softmax ----
    const int si = min(max(i - 3, 0), 57), sj = min(max(j - 3, 0), 57);
    const int vloi = si - r0, vloj = sj - c0;
    const int oi = r0 - i + 6, oj = c0 - j + 6;
    const float th = temp[head];
    float mx = -1e30f;
    #pragma unroll
    for (int mt = 0; mt < 13; ++mt) {
        int nb0 = mt * 16 + lq * 4;
        int rh0 = (nb0 * 2341) >> 15;
        int ch0 = nb0 - rh0 * 14;
        #pragma unroll
        for (int r = 0; r < 4; ++r) {
            int ch = ch0 + r, rh = rh0;
            if (ch >= 14) { ch -= 14; rh += 1; }
            int bidx = (rh + oi) * 13 + (ch + oj);
            float bias = rpbs[max(0, min(168, bidx))];
            bool valid = ((unsigned)(rh - vloi) <= 6u) && ((unsigned)(ch - vloj) <= 6u);
            float s = (acc[mt][r] + bias) * th;
            s = valid ? s : -1e30f;
            acc[mt][r] = s;
            mx = fmaxf(mx, s);
        }
    }
    mx = fmaxf(mx, __shfl_xor(mx, 16));
    mx = fmaxf(mx, __shfl_xor(mx, 32));
    float ssum = 0.f;
    #pragma unroll
    for (int mt = 0; mt < 13; ++mt)
        #pragma unroll
        for (int r = 0; r < 4; ++r) {
            float e = __expf(acc[mt][r] - mx);
            acc[mt][r] = e;
            ssum += e;
        }
    ssum += __shfl_xor(ssum, 16);
    ssum += __shfl_xor(ssum, 32);
    const float rs = 1.0f / ssum;

    if (lane < 32) {                       // zero Ps pad cols 208..223
        uint4 z4 = {0u, 0u, 0u, 0u};
        *(uint4*)&Ps[(w * 16 + (lane >> 1)) * 232 + 208 + (lane & 1) * 8] = z4;
    }
    #pragma unroll
    for (int mt = 0; mt < 13; ++mt) {
        unsigned lo = (unsigned)f2h(acc[mt][0] * rs) | ((unsigned)f2h(acc[mt][1] * rs) << 16);
        unsigned hi = (unsigned)f2h(acc[mt][2] * rs) | ((unsigned)f2h(acc[mt][3] * rs) << 16);
        *(uint2*)&Ps[px * 232 + mt * 16 + lq * 4] = make_uint2(lo, hi);
    }
    __syncthreads();

    // ---- PV: O[px][d] = P x V^T ----
    floatx4 oacc[2] = {};
    #pragma unroll
    for (int ks = 0; ks < 7; ++ks) {
        half8 ap = *(const half8*)&Ps[(w * 16 + lm) * 232 + ks * 32 + lq * 8];
        #pragma unroll
        for (int n2 = 0; n2 < 2; ++n2) {
            half8 bv = *(const half8*)&Vts[(n2 * 16 + lm) * 232 + ks * 32 + lq * 8];
            oacc[n2] = __builtin_amdgcn_mfma_f32_16x16x32_f16(ap, bv, oacc[n2], 0, 0, 0);
        }
    }
    #pragma unroll
    for (int n2 = 0; n2 < 2; ++n2)
        #pragma unroll
        for (int r = 0; r < 4; ++r) {
            int p2 = w * 16 + lq * 4 + r;
            int i2 = i0 + (p2 >> 3), j2 = j0 + (p2 & 7);
            attnO[((size_t)((b << 12) + (i2 << 6) + j2)) * 192 + head * 32 + n2 * 16 + lm]
                = f2bf(oacc[n2][r]);
        }
    __syncthreads();    // smem dead before next tile reuses it
}

// ---------------------------------------------------------------------------
// Phase 3: proj 1x1 as bf16 MFMA GEMM. M=8192 N=192 K=192.
// tile in [0,384): m-tile = tile & 127, n-tile = tile >> 7
// ---------------------------------------------------------------------------
__device__ void gp_tile(char* smem, int tile, const unsigned short* Ain,
    const float* Wp, const float* bp, float* out)
{
    unsigned short* As = (unsigned short*)smem;           // [64][200]
    unsigned short* Bs = (unsigned short*)(smem + 25600); // [64][200]
    const int t = threadIdx.x;
    const int m0 = (tile & 127) * 64;
    const int n0 = (tile >> 7) * 64;
    #pragma unroll
    for (int pass = 0; pass < 6; ++pass) {
        int idx = pass * 256 + t;
        int m = idx / 24, c16 = idx % 24;
        *(uint4*)&As[m * 200 + c16 * 8] = *(const uint4*)&Ain[(size_t)(m0 + m) * 192 + c16 * 8];
    }
    #pragma unroll
    for (int pass = 0; pass < 12; ++pass) {
        int idx = pass * 256 + t;
        int row = idx / 48, ch = idx - row * 48;
        float4 wv = *(const float4*)&Wp[(size_t)(n0 + row) * 192 + ch * 4];
        *(uint2*)&Bs[row * 200 + ch * 4] =
            make_uint2(f2bf2(wv.x, wv.y), f2bf2(wv.z, wv.w));
    }
    __syncthreads();
    const int w = t >> 6, lane = t & 63;
    const int lm = lane & 15, lq = lane >> 4;
    floatx4 acc[4] = {};
    #pragma unroll
    for (int ks = 0; ks < 6; ++ks) {
        short8 bf = *(const short8*)&Bs[(w * 16 + lm) * 200 + ks * 32 + lq * 8];
        #pragma unroll
        for (int mt = 0; mt < 4; ++mt) {
            short8 af = *(const short8*)&As[(mt * 16 + lm) * 200 + ks * 32 + lq * 8];
            acc[mt] = __builtin_amdgcn_mfma_f32_16x16x32_bf16(af, bf, acc[mt], 0, 0, 0);
        }
    }
    __syncthreads();
    float* fs = (float*)As;                 // [n][m] stride 68
    const float bias = bp[n0 + w * 16 + lm];
    #pragma unroll
    for (int mt = 0; mt < 4; ++mt)
        #pragma unroll
        for (int r = 0; r < 4; ++r)
            fs[(w * 16 + lm) * 68 + mt * 16 + lq * 4 + r] = acc[mt][r] + bias;
    __syncthreads();
    const int b = m0 >> 12, px0 = m0 & 4095;
    #pragma unroll
    for (int pass = 0; pass < 4; ++pass) {
        int idx = pass * 256 + t;           // 64 n x 16 m-quads
        int n = idx >> 4, m4 = idx & 15;
        float4 val = *(const float4*)&fs[n * 68 + m4 * 4];
        *(float4*)&out[((size_t)(b * 192 + n0 + n) << 12) + px0 + m4 * 4] = val;
    }
    __syncthreads();
}

// ---------------------------------------------------------------------------
// Single fused kernel, REGULAR launch (graph-capturable), hand-rolled grid
// barrier. 512 blocks x 256 thr; co-residency proven by LB(256,2) + 51.2KB
// LDS (see grid_barrier comment).
// ---------------------------------------------------------------------------
__global__ __launch_bounds__(256, 2) void k_fused(
    const float* __restrict__ x, const float* __restrict__ W1, const float* __restrict__ b1,
    const float* __restrict__ W2, const float* __restrict__ b2,
    const float* __restrict__ temp, const float* __restrict__ rpb,
    const float* __restrict__ Wp, const float* __restrict__ bp,
    unsigned short* __restrict__ qkv1b, unsigned short* __restrict__ attnO,
    float* __restrict__ out, unsigned* bar)
{
    __shared__ __align__(16) char smem[51200];

    for (int tile = blockIdx.x; tile < 1152; tile += 512)
        gq_tile(smem, tile, x, W1, b1, qkv1b);

    grid_barrier(bar, 512);

    for (int tile = blockIdx.x; tile < 768; tile += 512)
        attn_tile(smem, tile, qkv1b, W2, b2, temp, rpb, attnO);

    grid_barrier(bar, 1024);

    for (int tile = blockIdx.x; tile < 384; tile += 512)
        gp_tile(smem, tile, attnO, Wp, bp, out);
}

extern "C" void kernel_launch(void* const* d_in, const int* in_sizes, int n_in,
                              void* d_out, int out_size, void* d_ws, size_t ws_size,
                              hipStream_t stream) {
    const float* x    = (const float*)d_in[0];
    const float* W1   = (const float*)d_in[1];
    const float* b1   = (const float*)d_in[2];
    const float* W2   = (const float*)d_in[3];
    const float* b2   = (const float*)d_in[4];
    const float* temp = (const float*)d_in[5];
    const float* rpb  = (const float*)d_in[6];
    const float* Wp   = (const float*)d_in[7];
    const float* bp   = (const float*)d_in[8];
    float* out = (float*)d_out;

    char* ws = (char*)d_ws;
    unsigned short* qkv1b = (unsigned short*)(ws);
    unsigned short* attnO = (unsigned short*)(ws + 9437184);
    unsigned* bar         = (unsigned*)(ws + 16777216);

    // barrier counter must start at 0 each launch (ws is poisoned per iter)
    hipMemsetAsync(bar, 0, 64, stream);

    k_fused<<<dim3(512), dim3(256), 0, stream>>>(
        x, W1, b1, W2, b2, temp, rpb, Wp, bp, qkv1b, attnO, out, bar);
}

// Round 6
// 123.245 us; speedup vs baseline: 2.2141x; 2.2141x over previous
//
#include <hip/hip_runtime.h>
#include <math.h>

typedef __attribute__((ext_vector_type(8))) short short8;
typedef __attribute__((ext_vector_type(8))) _Float16 half8;
typedef __attribute__((ext_vector_type(4))) float floatx4;

// ---- bf16 helpers (round-to-nearest-even) ----
__device__ inline float bflo(unsigned u) { return __uint_as_float(u << 16); }
__device__ inline float bfhi(unsigned u) { return __uint_as_float(u & 0xffff0000u); }
__device__ inline unsigned short f2bf(float x) {
    unsigned u = __float_as_uint(x);
    return (unsigned short)((u + 0x7fffu + ((u >> 16) & 1u)) >> 16);
}
__device__ inline unsigned f2bf2(float lo, float hi) {
    unsigned a = __float_as_uint(lo), b = __float_as_uint(hi);
    a = (a + 0x7fffu + ((a >> 16) & 1u)) >> 16;
    b = (b + 0x7fffu + ((b >> 16) & 1u)) & 0xffff0000u;
    return a | b;
}
__device__ inline unsigned short f2h(float x) {
    _Float16 h = (_Float16)x;
    return __builtin_bit_cast(unsigned short, h);
}

// ws layout (bytes):
//   qkv1b @ 0        : 2*18*4096*32*2 = 9437184  bf16 [b][g][px][32] (pre-dw)
//   attnO @ 9437184  : 2*4096*192*2 = 3145728    bf16 [b*px][c]

// ---------------------------------------------------------------------------
// K1: QKV 1x1 conv as bf16 MFMA GEMM, M=8192(px) N=576(oc) K=192.
// NEW: each block stages its A-tile (transpose+convert of x, the expensive
// part) ONCE and loops over 3 n-tiles (grid 128x3 instead of 128x9).
// Epilogue stages through Bs (dead after MFMA) so As survives the loop.
// Cuts x re-reads 9x -> 3x (225 -> 75 MB of L3/HBM traffic) and A-staging
// VALU work 3x. B-staging unchanged.
// ---------------------------------------------------------------------------
__global__ __launch_bounds__(256) void k_gq(const float* __restrict__ x,
    const float* __restrict__ W1, const float* __restrict__ b1,
    unsigned short* __restrict__ qkv)
{
    __shared__ __align__(16) unsigned short As[64 * 200];
    __shared__ __align__(16) unsigned short Bs[64 * 200];
    const int t = threadIdx.x;
    const int m0 = blockIdx.x * 64;
    const int w = t >> 6, lane = t & 63;
    const int b = m0 >> 12, px0 = m0 & 4095;
    // ---- A: transpose-convert 64px x 192c (ONCE per block) ----
    {
        const float* xb = x + ((size_t)(b * 192) << 12) + px0 + lane;
        const int cb = w * 48;
        #pragma unroll
        for (int r4 = 0; r4 < 12; ++r4) {
            float v0 = xb[(size_t)(cb + r4 * 4 + 0) << 12];
            float v1 = xb[(size_t)(cb + r4 * 4 + 1) << 12];
            float v2 = xb[(size_t)(cb + r4 * 4 + 2) << 12];
            float v3 = xb[(size_t)(cb + r4 * 4 + 3) << 12];
            *(uint2*)&As[lane * 200 + cb + r4 * 4] =
                make_uint2(f2bf2(v0, v1), f2bf2(v2, v3));
        }
    }
    const int lm = lane & 15, lq = lane >> 4;
    for (int nt = 0; nt < 3; ++nt) {
        const int n0 = blockIdx.y * 192 + nt * 64;
        // ---- B: convert W1 slice [n0..n0+63][192] ----
        #pragma unroll
        for (int pass = 0; pass < 12; ++pass) {
            int idx = pass * 256 + t;
            int row = idx / 48, ch = idx - row * 48;
            float4 wv = *(const float4*)&W1[(size_t)(n0 + row) * 192 + ch * 4];
            *(uint2*)&Bs[row * 200 + ch * 4] =
                make_uint2(f2bf2(wv.x, wv.y), f2bf2(wv.z, wv.w));
        }
        __syncthreads();     // (covers A-stage on first iteration)
        floatx4 acc[4] = {};
        #pragma unroll
        for (int ks = 0; ks < 6; ++ks) {
            short8 bf = *(const short8*)&Bs[(w * 16 + lm) * 200 + ks * 32 + lq * 8];
            #pragma unroll
            for (int mt = 0; mt < 4; ++mt) {
                short8 af = *(const short8*)&As[(mt * 16 + lm) * 200 + ks * 32 + lq * 8];
                acc[mt] = __builtin_amdgcn_mfma_f32_16x16x32_bf16(af, bf, acc[mt], 0, 0, 0);
            }
        }
        __syncthreads();     // Bs dead; reuse as epilogue staging
        const float bias = b1[n0 + w * 16 + lm];
        #pragma unroll
        for (int mt = 0; mt < 4; ++mt)
            #pragma unroll
            for (int r = 0; r < 4; ++r)
                Bs[(mt * 16 + lq * 4 + r) * 72 + w * 16 + lm] = f2bf(acc[mt][r] + bias);
        __syncthreads();
        #pragma unroll
        for (int pass = 0; pass < 2; ++pass) {
            int idx = pass * 256 + t;           // 64 m x 8 n-groups
            int m = idx >> 3, n8 = idx & 7;
            uint4 val = *(const uint4*)&Bs[m * 72 + n8 * 8];
            int oc = n0 + n8 * 8;
            int g = oc >> 5, d = oc & 31;
            *(uint4*)&qkv[((((size_t)(b * 18 + g) << 12) + px0 + m) << 5) + d] = val;
        }
        __syncthreads();     // Bs dead before next n-tile stages into it
    }
}

// ---------------------------------------------------------------------------
// K2: MFMA neighborhood attention with FUSED depthwise 3x3 (R1-verified
// structure: dw computed from global halo reads, L2-resident).
// Block 256 = (b, head, 8x8 tile), 4 waves.
// ---------------------------------------------------------------------------
__global__ __launch_bounds__(256) void k_attn(const unsigned short* __restrict__ qkv,
    const float* __restrict__ W2, const float* __restrict__ b2,
    const float* __restrict__ temp, const float* __restrict__ rpb,
    unsigned short* __restrict__ attnO)
{
    __shared__ __align__(16) char lds[49088];
    unsigned short* Ks  = (unsigned short*)lds;            // [208][40] bf16
    unsigned short* Ps  = (unsigned short*)lds;            // [64][232] f16 (alias)
    unsigned short* Vts = (unsigned short*)(lds + 29696);  // [32][232] f16
    float* rpbs = (float*)(lds + 44544);                   // [169]
    float* dwW  = (float*)(lds + 45248);                   // [3][9][32] plane-major
    float* dwB  = (float*)(lds + 48704);                   // [3][32]

    const int t = threadIdx.x;
    const int head = blockIdx.y, b = blockIdx.z;

    // ---- stage dw weights/bias + rpb ----
    for (int idx = t; idx < 864; idx += 256) {
        int plane = idx / 288, rem = idx - plane * 288;
        dwW[idx] = W2[(plane * 192 + head * 32 + (rem & 31)) * 9 + (rem >> 5)];
    }
    if (t < 96) dwB[t] = b2[(t >> 5) * 192 + head * 32 + (t & 31)];
    if (t < 169) rpbs[t] = rpb[head * 169 + t];
    __syncthreads();

    const int ti = blockIdx.x >> 3, tj = blockIdx.x & 7;
    const int i0 = ti * 8, j0 = tj * 8;
    const int r0 = min(max(i0 - 3, 0), 50), c0 = min(max(j0 - 3, 0), 50);
    const unsigned short* qpl = qkv + ((size_t)(b * 18 + head) << 17);
    const unsigned short* kpl = qkv + ((size_t)(b * 18 + 6 + head) << 17);
    const unsigned short* vpl = qkv + ((size_t)(b * 18 + 12 + head) << 17);

    // ---- stage K-hat (dw + l2norm, bf16) and V^T (dw, f16) ----
    if (t < 196) {
        int r = (t * 2341) >> 15, cc = t - r * 14;
        const int pi = r0 + r, pj = c0 + cc;
        float acc[32];
        // K plane depthwise
        #pragma unroll
        for (int e = 0; e < 32; ++e) acc[e] = dwB[32 + e];
        #pragma unroll
        for (int di = -1; di <= 1; ++di) {
            int ii = pi + di;
            if (ii < 0 || ii > 63) continue;
            #pragma unroll
            for (int dj = -1; dj <= 1; ++dj) {
                int jj = pj + dj;
                if (jj < 0 || jj > 63) continue;
                const float* wt = &dwW[(9 + (di + 1) * 3 + dj + 1) * 32];
                const uint4* kg = (const uint4*)(kpl + (((ii << 6) + jj) << 5));
                #pragma unroll
                for (int q = 0; q < 4; ++q) {
                    uint4 u = kg[q];
                    unsigned uu[4] = {u.x, u.y, u.z, u.w};
                    #pragma unroll
                    for (int e = 0; e < 4; ++e) {
                        acc[q * 8 + e * 2]     = fmaf(bflo(uu[e]), wt[q * 8 + e * 2],     acc[q * 8 + e * 2]);
                        acc[q * 8 + e * 2 + 1] = fmaf(bfhi(uu[e]), wt[q * 8 + e * 2 + 1], acc[q * 8 + e * 2 + 1]);
                    }
                }
            }
        }
        float ss = 0.f;
        #pragma unroll
        for (int e = 0; e < 32; ++e) ss = fmaf(acc[e], acc[e], ss);
        float rinv = 1.0f / fmaxf(sqrtf(ss), 1e-12f);
        #pragma unroll
        for (int q = 0; q < 4; ++q) {
            uint4 p;
            p.x = f2bf2(acc[q * 8 + 0] * rinv, acc[q * 8 + 1] * rinv);
            p.y = f2bf2(acc[q * 8 + 2] * rinv, acc[q * 8 + 3] * rinv);
            p.z = f2bf2(acc[q * 8 + 4] * rinv, acc[q * 8 + 5] * rinv);
            p.w = f2bf2(acc[q * 8 + 6] * rinv, acc[q * 8 + 7] * rinv);
            *(uint4*)&Ks[t * 40 + q * 8] = p;
        }
        // V plane depthwise -> transposed f16
        #pragma unroll
        for (int e = 0; e < 32; ++e) acc[e] = dwB[64 + e];
        #pragma unroll
        for (int di = -1; di <= 1; ++di) {
            int ii = pi + di;
            if (ii < 0 || ii > 63) continue;
            #pragma unroll
            for (int dj = -1; dj <= 1; ++dj) {
                int jj = pj + dj;
                if (jj < 0 || jj > 63) continue;
                const float* wt = &dwW[(18 + (di + 1) * 3 + dj + 1) * 32];
                const uint4* vg = (const uint4*)(vpl + (((ii << 6) + jj) << 5));
                #pragma unroll
                for (int q = 0; q < 4; ++q) {
                    uint4 u = vg[q];
                    unsigned uu[4] = {u.x, u.y, u.z, u.w};
                    #pragma unroll
                    for (int e = 0; e < 4; ++e) {
                        acc[q * 8 + e * 2]     = fmaf(bflo(uu[e]), wt[q * 8 + e * 2],     acc[q * 8 + e * 2]);
                        acc[q * 8 + e * 2 + 1] = fmaf(bfhi(uu[e]), wt[q * 8 + e * 2 + 1], acc[q * 8 + e * 2 + 1]);
                    }
                }
            }
        }
        #pragma unroll
        for (int e = 0; e < 32; ++e) Vts[e * 232 + t] = f2h(acc[e]);
    }
    // zero V^T cols 196..223 (PV pad region must be 0)
    for (int idx = t; idx < 448; idx += 256) {
        int row = (idx * 2341) >> 15;
        int c = idx - row * 14;
        ((unsigned*)(Vts + row * 232))[98 + c] = 0u;
    }

    // ---- q: fused dw + l2norm, fragment in registers ----
    const int w = t >> 6, lane = t & 63;
    const int lm = lane & 15, lq = lane >> 4;
    const int px = w * 16 + lm;
    const int i = i0 + (px >> 3), j = j0 + (px & 7);
    float qf[8];
    #pragma unroll
    for (int e = 0; e < 8; ++e) qf[e] = dwB[lq * 8 + e];
    #pragma unroll
    for (int di = -1; di <= 1; ++di) {
        int ii = i + di;
        if (ii < 0 || ii > 63) continue;
        #pragma unroll
        for (int dj = -1; dj <= 1; ++dj) {
            int jj = j + dj;
            if (jj < 0 || jj > 63) continue;
            const float* wt = &dwW[((di + 1) * 3 + dj + 1) * 32 + lq * 8];
            uint4 u = *(const uint4*)(qpl + ((((ii << 6) + jj) << 5) + lq * 8));
            unsigned uu[4] = {u.x, u.y, u.z, u.w};
            #pragma unroll
            for (int e = 0; e < 4; ++e) {
                qf[e * 2]     = fmaf(bflo(uu[e]), wt[e * 2],     qf[e * 2]);
                qf[e * 2 + 1] = fmaf(bfhi(uu[e]), wt[e * 2 + 1], qf[e * 2 + 1]);
            }
        }
    }
    float qs = 0.f;
    #pragma unroll
    for (int e = 0; e < 8; ++e) qs = fmaf(qf[e], qf[e], qs);
    qs += __shfl_xor(qs, 16);
    qs += __shfl_xor(qs, 32);
    float qinv = 1.0f / fmaxf(sqrtf(qs), 1e-12f);
    short8 bq;
    #pragma unroll
    for (int e = 0; e < 8; ++e) bq[e] = (short)f2bf(qf[e] * qinv);
    __syncthreads();

    // ---- QK^T: S^T[nbr][px], 13 n-tiles of 16 nbrs ----
    floatx4 acc[13];
    #pragma unroll
    for (int mt = 0; mt < 13; ++mt) {
        short8 ak = *(const short8*)&Ks[(mt * 16 + lm) * 40 + lq * 8];
        floatx4 z = {0.f, 0.f, 0.f, 0.f};
        acc[mt] = __builtin_amdgcn_mfma_f32_16x16x32_bf16(ak, bq, z, 0, 0, 0);
    }
    __syncthreads();                        // Ks dead; Ps may overwrite

    // ---- mask + bias + softmax ----
    const int si = min(max(i - 3, 0), 57), sj = min(max(j - 3, 0), 57);
    const int vloi = si - r0, vloj = sj - c0;
    const int oi = r0 - i + 6, oj = c0 - j + 6;
    const float th = temp[head];
    float mx = -1e30f;
    #pragma unroll
    for (int mt = 0; mt < 13; ++mt) {
        int nb0 = mt * 16 + lq * 4;
        int rh0 = (nb0 * 2341) >> 15;
        int ch0 = nb0 - rh0 * 14;
        #pragma unroll
        for (int r = 0; r < 4; ++r) {
            int ch = ch0 + r, rh = rh0;
            if (ch >= 14) { ch -= 14; rh += 1; }
            int bidx = (rh + oi) * 13 + (ch + oj);
            float bias = rpbs[max(0, min(168, bidx))];
            bool valid = ((unsigned)(rh - vloi) <= 6u) && ((unsigned)(ch - vloj) <= 6u);
            float s = (acc[mt][r] + bias) * th;
            s = valid ? s : -1e30f;
            acc[mt][r] = s;
            mx = fmaxf(mx, s);
        }
    }
    mx = fmaxf(mx, __shfl_xor(mx, 16));
    mx = fmaxf(mx, __shfl_xor(mx, 32));
    float ssum = 0.f;
    #pragma unroll
    for (int mt = 0; mt < 13; ++mt)
        #pragma unroll
        for (int r = 0; r < 4; ++r) {
            float e = __expf(acc[mt][r] - mx);
            acc[mt][r] = e;
            ssum += e;
        }
    ssum += __shfl_xor(ssum, 16);
    ssum += __shfl_xor(ssum, 32);
    const float rs = 1.0f / ssum;

    if (lane < 32) {                       // zero Ps pad cols 208..223
        uint4 z4 = {0u, 0u, 0u, 0u};
        *(uint4*)&Ps[(w * 16 + (lane >> 1)) * 232 + 208 + (lane & 1) * 8] = z4;
    }
    #pragma unroll
    for (int mt = 0; mt < 13; ++mt) {
        unsigned lo = (unsigned)f2h(acc[mt][0] * rs) | ((unsigned)f2h(acc[mt][1] * rs) << 16);
        unsigned hi = (unsigned)f2h(acc[mt][2] * rs) | ((unsigned)f2h(acc[mt][3] * rs) << 16);
        *(uint2*)&Ps[px * 232 + mt * 16 + lq * 4] = make_uint2(lo, hi);
    }
    __syncthreads();

    // ---- PV: O[px][d] = P x V^T ----
    floatx4 oacc[2] = {};
    #pragma unroll
    for (int ks = 0; ks < 7; ++ks) {
        half8 ap = *(const half8*)&Ps[(w * 16 + lm) * 232 + ks * 32 + lq * 8];
        #pragma unroll
        for (int n2 = 0; n2 < 2; ++n2) {
            half8 bv = *(const half8*)&Vts[(n2 * 16 + lm) * 232 + ks * 32 + lq * 8];
            oacc[n2] = __builtin_amdgcn_mfma_f32_16x16x32_f16(ap, bv, oacc[n2], 0, 0, 0);
        }
    }
    #pragma unroll
    for (int n2 = 0; n2 < 2; ++n2)
        #pragma unroll
        for (int r = 0; r < 4; ++r) {
            int p2 = w * 16 + lq * 4 + r;
            int i2 = i0 + (p2 >> 3), j2 = j0 + (p2 & 7);
            attnO[((size_t)((b << 12) + (i2 << 6) + j2)) * 192 + head * 32 + n2 * 16 + lm]
                = f2bf(oacc[n2][r]);
        }
}

// ---------------------------------------------------------------------------
// K4: proj 1x1 as bf16 MFMA GEMM. M=8192 N=192 K=192. (unchanged)
// ---------------------------------------------------------------------------
__global__ __launch_bounds__(256) void k_gp(const unsigned short* __restrict__ Ain,
    const float* __restrict__ Wp, const float* __restrict__ bp,
    float* __restrict__ out)
{
    __shared__ __align__(16) unsigned short As[64 * 200];
    __shared__ __align__(16) unsigned short Bs[64 * 200];
    const int t = threadIdx.x;
    const int m0 = blockIdx.x * 64;
    const int n0 = blockIdx.y * 64;
    #pragma unroll
    for (int pass = 0; pass < 6; ++pass) {
        int idx = pass * 256 + t;
        int m = idx / 24, c16 = idx % 24;
        *(uint4*)&As[m * 200 + c16 * 8] = *(const uint4*)&Ain[(size_t)(m0 + m) * 192 + c16 * 8];
    }
    #pragma unroll
    for (int pass = 0; pass < 12; ++pass) {
        int idx = pass * 256 + t;
        int row = idx / 48, ch = idx - row * 48;
        float4 wv = *(const float4*)&Wp[(size_t)(n0 + row) * 192 + ch * 4];
        *(uint2*)&Bs[row * 200 + ch * 4] =
            make_uint2(f2bf2(wv.x, wv.y), f2bf2(wv.z, wv.w));
    }
    __syncthreads();
    const int w = t >> 6, lane = t & 63;
    const int lm = lane & 15, lq = lane >> 4;
    floatx4 acc[4] = {};
    #pragma unroll
    for (int ks = 0; ks < 6; ++ks) {
        short8 bf = *(const short8*)&Bs[(w * 16 + lm) * 200 + ks * 32 + lq * 8];
        #pragma unroll
        for (int mt = 0; mt < 4; ++mt) {
            short8 af = *(const short8*)&As[(mt * 16 + lm) * 200 + ks * 32 + lq * 8];
            acc[mt] = __builtin_amdgcn_mfma_f32_16x16x32_bf16(af, bf, acc[mt], 0, 0, 0);
        }
    }
    __syncthreads();
    float* fs = (float*)As;                 // [n][m] stride 68
    const float bias = bp[n0 + w * 16 + lm];
    #pragma unroll
    for (int mt = 0; mt < 4; ++mt)
        #pragma unroll
        for (int r = 0; r < 4; ++r)
            fs[(w * 16 + lm) * 68 + mt * 16 + lq * 4 + r] = acc[mt][r] + bias;
    __syncthreads();
    const int b = m0 >> 12, px0 = m0 & 4095;
    #pragma unroll
    for (int pass = 0; pass < 4; ++pass) {
        int idx = pass * 256 + t;           // 64 n x 16 m-quads
        int n = idx >> 4, m4 = idx & 15;
        float4 val = *(const float4*)&fs[n * 68 + m4 * 4];
        *(float4*)&out[((size_t)(b * 192 + n0 + n) << 12) + px0 + m4 * 4] = val;
    }
}

extern "C" void kernel_launch(void* const* d_in, const int* in_sizes, int n_in,
                              void* d_out, int out_size, void* d_ws, size_t ws_size,
                              hipStream_t stream) {
    const float* x    = (const float*)d_in[0];
    const float* W1   = (const float*)d_in[1];
    const float* b1   = (const float*)d_in[2];
    const float* W2   = (const float*)d_in[3];
    const float* b2   = (const float*)d_in[4];
    const float* temp = (const float*)d_in[5];
    const float* rpb  = (const float*)d_in[6];
    const float* Wp   = (const float*)d_in[7];
    const float* bp   = (const float*)d_in[8];
    float* out = (float*)d_out;

    char* ws = (char*)d_ws;
    unsigned short* qkv1b = (unsigned short*)(ws);
    unsigned short* attnO = (unsigned short*)(ws + 9437184);

    k_gq  <<<dim3(128, 3), 256, 0, stream>>>(x, W1, b1, qkv1b);
    k_attn<<<dim3(64, 6, 2), 256, 0, stream>>>(qkv1b, W2, b2, temp, rpb, attnO);
    k_gp  <<<dim3(128, 3), 256, 0, stream>>>(attnO, Wp, bp, out);
}

// Round 7
// 116.499 us; speedup vs baseline: 2.3423x; 1.0579x over previous
//
#include <hip/hip_runtime.h>
#include <math.h>

typedef __attribute__((ext_vector_type(8))) short short8;
typedef __attribute__((ext_vector_type(8))) _Float16 half8;
typedef __attribute__((ext_vector_type(4))) float floatx4;

// ---- bf16 helpers (round-to-nearest-even) ----
__device__ inline float bflo(unsigned u) { return __uint_as_float(u << 16); }
__device__ inline float bfhi(unsigned u) { return __uint_as_float(u & 0xffff0000u); }
__device__ inline unsigned short f2bf(float x) {
    unsigned u = __float_as_uint(x);
    return (unsigned short)((u + 0x7fffu + ((u >> 16) & 1u)) >> 16);
}
__device__ inline unsigned f2bf2(float lo, float hi) {
    unsigned a = __float_as_uint(lo), b = __float_as_uint(hi);
    a = (a + 0x7fffu + ((a >> 16) & 1u)) >> 16;
    b = (b + 0x7fffu + ((b >> 16) & 1u)) & 0xffff0000u;
    return a | b;
}
__device__ inline unsigned short f2h(float x) {
    _Float16 h = (_Float16)x;
    return __builtin_bit_cast(unsigned short, h);
}

// ws layout (bytes):
//   qkv1b @ 0        : 2*18*4096*32*2 = 9437184  bf16 [b][g][px][32] (pre-dw)
//   attnO @ 9437184  : 2*4096*192*2 = 3145728    bf16 [b*px][c]
//   xT    @ 12582912 : 2*4096*192*2 = 3145728    bf16 [b*px][c] (transposed x)

// ---------------------------------------------------------------------------
// K0: one-shot transpose+convert  x fp32 [b][c][px] -> xT bf16 [b*px][c].
// 128 blocks x 256 thr. Strided fp32 reads (wave-coalesced 256B) staged via
// LDS, then fully contiguous uint4 writes. Factors the expensive transpose
// out of k_gq, which previously redid it 9x per A-tile.
// ---------------------------------------------------------------------------
__global__ __launch_bounds__(256) void k_tr(const float* __restrict__ x,
    unsigned short* __restrict__ xT)
{
    __shared__ __align__(16) unsigned short As[64 * 200];
    const int t = threadIdx.x;
    const int m0 = blockIdx.x * 64;
    const int w = t >> 6, lane = t & 63;
    const int b = m0 >> 12, px0 = m0 & 4095;
    {
        const float* xb = x + ((size_t)(b * 192) << 12) + px0 + lane;
        const int cb = w * 48;
        #pragma unroll
        for (int r4 = 0; r4 < 12; ++r4) {
            float v0 = xb[(size_t)(cb + r4 * 4 + 0) << 12];
            float v1 = xb[(size_t)(cb + r4 * 4 + 1) << 12];
            float v2 = xb[(size_t)(cb + r4 * 4 + 2) << 12];
            float v3 = xb[(size_t)(cb + r4 * 4 + 3) << 12];
            *(uint2*)&As[lane * 200 + cb + r4 * 4] =
                make_uint2(f2bf2(v0, v1), f2bf2(v2, v3));
        }
    }
    __syncthreads();
    #pragma unroll
    for (int pass = 0; pass < 6; ++pass) {
        int idx = pass * 256 + t;           // 64 rows x 24 col-octets
        int m = idx / 24, c16 = idx % 24;
        *(uint4*)&xT[(size_t)(m0 + m) * 192 + c16 * 8] =
            *(const uint4*)&As[m * 200 + c16 * 8];
    }
}

// ---------------------------------------------------------------------------
// K1: QKV 1x1 conv as bf16 MFMA GEMM, M=8192(px) N=576(oc) K=192.
// Grid back to the verified 128x9 (R6's 3-n-tile loop regressed: occupancy
// beats traffic). A now loads contiguously from xT (6 uint4 passes, no
// transpose, no convert) — the per-block A-path cost drops ~4x.
// ---------------------------------------------------------------------------
__global__ __launch_bounds__(256) void k_gq(const unsigned short* __restrict__ xT,
    const float* __restrict__ W1, const float* __restrict__ b1,
    unsigned short* __restrict__ qkv)
{
    __shared__ __align__(16) unsigned short As[64 * 200];
    __shared__ __align__(16) unsigned short Bs[64 * 200];
    const int t = threadIdx.x;
    const int m0 = blockIdx.x * 64;
    const int n0 = blockIdx.y * 64;
    const int w = t >> 6, lane = t & 63;
    const int b = m0 >> 12, px0 = m0 & 4095;
    // ---- A: contiguous bf16 load from xT ----
    #pragma unroll
    for (int pass = 0; pass < 6; ++pass) {
        int idx = pass * 256 + t;
        int m = idx / 24, c16 = idx % 24;
        *(uint4*)&As[m * 200 + c16 * 8] = *(const uint4*)&xT[(size_t)(m0 + m) * 192 + c16 * 8];
    }
    // ---- B: convert W1 slice [n0..n0+63][192] ----
    #pragma unroll
    for (int pass = 0; pass < 12; ++pass) {
        int idx = pass * 256 + t;
        int row = idx / 48, ch = idx - row * 48;
        float4 wv = *(const float4*)&W1[(size_t)(n0 + row) * 192 + ch * 4];
        *(uint2*)&Bs[row * 200 + ch * 4] =
            make_uint2(f2bf2(wv.x, wv.y), f2bf2(wv.z, wv.w));
    }
    __syncthreads();
    const int lm = lane & 15, lq = lane >> 4;
    floatx4 acc[4] = {};
    #pragma unroll
    for (int ks = 0; ks < 6; ++ks) {
        short8 bf = *(const short8*)&Bs[(w * 16 + lm) * 200 + ks * 32 + lq * 8];
        #pragma unroll
        for (int mt = 0; mt < 4; ++mt) {
            short8 af = *(const short8*)&As[(mt * 16 + lm) * 200 + ks * 32 + lq * 8];
            acc[mt] = __builtin_amdgcn_mfma_f32_16x16x32_bf16(af, bf, acc[mt], 0, 0, 0);
        }
    }
    __syncthreads();
    const float bias = b1[n0 + w * 16 + lm];
    #pragma unroll
    for (int mt = 0; mt < 4; ++mt)
        #pragma unroll
        for (int r = 0; r < 4; ++r)
            As[(mt * 16 + lq * 4 + r) * 72 + w * 16 + lm] = f2bf(acc[mt][r] + bias);
    __syncthreads();
    #pragma unroll
    for (int pass = 0; pass < 2; ++pass) {
        int idx = pass * 256 + t;           // 64 m x 8 n-groups
        int m = idx >> 3, n8 = idx & 7;
        uint4 val = *(const uint4*)&As[m * 72 + n8 * 8];
        int oc = n0 + n8 * 8;
        int g = oc >> 5, d = oc & 31;
        *(uint4*)&qkv[((((size_t)(b * 18 + g) << 12) + px0 + m) << 5) + d] = val;
    }
}

// ---------------------------------------------------------------------------
// K2: MFMA neighborhood attention with FUSED depthwise 3x3 (R1-verified
// structure: dw computed from global halo reads, L2-resident).
// Block 256 = (b, head, 8x8 tile), 4 waves.
// ---------------------------------------------------------------------------
__global__ __launch_bounds__(256) void k_attn(const unsigned short* __restrict__ qkv,
    const float* __restrict__ W2, const float* __restrict__ b2,
    const float* __restrict__ temp, const float* __restrict__ rpb,
    unsigned short* __restrict__ attnO)
{
    __shared__ __align__(16) char lds[49088];
    unsigned short* Ks  = (unsigned short*)lds;            // [208][40] bf16
    unsigned short* Ps  = (unsigned short*)lds;            // [64][232] f16 (alias)
    unsigned short* Vts = (unsigned short*)(lds + 29696);  // [32][232] f16
    float* rpbs = (float*)(lds + 44544);                   // [169]
    float* dwW  = (float*)(lds + 45248);                   // [3][9][32] plane-major
    float* dwB  = (float*)(lds + 48704);                   // [3][32]

    const int t = threadIdx.x;
    const int head = blockIdx.y, b = blockIdx.z;

    // ---- stage dw weights/bias + rpb ----
    for (int idx = t; idx < 864; idx += 256) {
        int plane = idx / 288, rem = idx - plane * 288;
        dwW[idx] = W2[(plane * 192 + head * 32 + (rem & 31)) * 9 + (rem >> 5)];
    }
    if (t < 96) dwB[t] = b2[(t >> 5) * 192 + head * 32 + (t & 31)];
    if (t < 169) rpbs[t] = rpb[head * 169 + t];
    __syncthreads();

    const int ti = blockIdx.x >> 3, tj = blockIdx.x & 7;
    const int i0 = ti * 8, j0 = tj * 8;
    const int r0 = min(max(i0 - 3, 0), 50), c0 = min(max(j0 - 3, 0), 50);
    const unsigned short* qpl = qkv + ((size_t)(b * 18 + head) << 17);
    const unsigned short* kpl = qkv + ((size_t)(b * 18 + 6 + head) << 17);
    const unsigned short* vpl = qkv + ((size_t)(b * 18 + 12 + head) << 17);

    // ---- stage K-hat (dw + l2norm, bf16) and V^T (dw, f16) ----
    if (t < 196) {
        int r = (t * 2341) >> 15, cc = t - r * 14;
        const int pi = r0 + r, pj = c0 + cc;
        float acc[32];
        // K plane depthwise
        #pragma unroll
        for (int e = 0; e < 32; ++e) acc[e] = dwB[32 + e];
        #pragma unroll
        for (int di = -1; di <= 1; ++di) {
            int ii = pi + di;
            if (ii < 0 || ii > 63) continue;
            #pragma unroll
            for (int dj = -1; dj <= 1; ++dj) {
                int jj = pj + dj;
                if (jj < 0 || jj > 63) continue;
                const float* wt = &dwW[(9 + (di + 1) * 3 + dj + 1) * 32];
                const uint4* kg = (const uint4*)(kpl + (((ii << 6) + jj) << 5));
                #pragma unroll
                for (int q = 0; q < 4; ++q) {
                    uint4 u = kg[q];
                    unsigned uu[4] = {u.x, u.y, u.z, u.w};
                    #pragma unroll
                    for (int e = 0; e < 4; ++e) {
                        acc[q * 8 + e * 2]     = fmaf(bflo(uu[e]), wt[q * 8 + e * 2],     acc[q * 8 + e * 2]);
                        acc[q * 8 + e * 2 + 1] = fmaf(bfhi(uu[e]), wt[q * 8 + e * 2 + 1], acc[q * 8 + e * 2 + 1]);
                    }
                }
            }
        }
        float ss = 0.f;
        #pragma unroll
        for (int e = 0; e < 32; ++e) ss = fmaf(acc[e], acc[e], ss);
        float rinv = 1.0f / fmaxf(sqrtf(ss), 1e-12f);
        #pragma unroll
        for (int q = 0; q < 4; ++q) {
            uint4 p;
            p.x = f2bf2(acc[q * 8 + 0] * rinv, acc[q * 8 + 1] * rinv);
            p.y = f2bf2(acc[q * 8 + 2] * rinv, acc[q * 8 + 3] * rinv);
            p.z = f2bf2(acc[q * 8 + 4] * rinv, acc[q * 8 + 5] * rinv);
            p.w = f2bf2(acc[q * 8 + 6] * rinv, acc[q * 8 + 7] * rinv);
            *(uint4*)&Ks[t * 40 + q * 8] = p;
        }
        // V plane depthwise -> transposed f16
        #pragma unroll
        for (int e = 0; e < 32; ++e) acc[e] = dwB[64 + e];
        #pragma unroll
        for (int di = -1; di <= 1; ++di) {
            int ii = pi + di;
            if (ii < 0 || ii > 63) continue;
            #pragma unroll
            for (int dj = -1; dj <= 1; ++dj) {
                int jj = pj + dj;
                if (jj < 0 || jj > 63) continue;
                const float* wt = &dwW[(18 + (di + 1) * 3 + dj + 1) * 32];
                const uint4* vg = (const uint4*)(vpl + (((ii << 6) + jj) << 5));
                #pragma unroll
                for (int q = 0; q < 4; ++q) {
                    uint4 u = vg[q];
                    unsigned uu[4] = {u.x, u.y, u.z, u.w};
                    #pragma unroll
                    for (int e = 0; e < 4; ++e) {
                        acc[q * 8 + e * 2]     = fmaf(bflo(uu[e]), wt[q * 8 + e * 2],     acc[q * 8 + e * 2]);
                        acc[q * 8 + e * 2 + 1] = fmaf(bfhi(uu[e]), wt[q * 8 + e * 2 + 1], acc[q * 8 + e * 2 + 1]);
                    }
                }
            }
        }
        #pragma unroll
        for (int e = 0; e < 32; ++e) Vts[e * 232 + t] = f2h(acc[e]);
    }
    // zero V^T cols 196..223 (PV pad region must be 0)
    for (int idx = t; idx < 448; idx += 256) {
        int row = (idx * 2341) >> 15;
        int c = idx - row * 14;
        ((unsigned*)(Vts + row * 232))[98 + c] = 0u;
    }

    // ---- q: fused dw + l2norm, fragment in registers ----
    const int w = t >> 6, lane = t & 63;
    const int lm = lane & 15, lq = lane >> 4;
    const int px = w * 16 + lm;
    const int i = i0 + (px >> 3), j = j0 + (px & 7);
    float qf[8];
    #pragma unroll
    for (int e = 0; e < 8; ++e) qf[e] = dwB[lq * 8 + e];
    #pragma unroll
    for (int di = -1; di <= 1; ++di) {
        int ii = i + di;
        if (ii < 0 || ii > 63) continue;
        #pragma unroll
        for (int dj = -1; dj <= 1; ++dj) {
            int jj = j + dj;
            if (jj < 0 || jj > 63) continue;
            const float* wt = &dwW[((di + 1) * 3 + dj + 1) * 32 + lq * 8];
            uint4 u = *(const uint4*)(qpl + ((((ii << 6) + jj) << 5) + lq * 8));
            unsigned uu[4] = {u.x, u.y, u.z, u.w};
            #pragma unroll
            for (int e = 0; e < 4; ++e) {
                qf[e * 2]     = fmaf(bflo(uu[e]), wt[e * 2],     qf[e * 2]);
                qf[e * 2 + 1] = fmaf(bfhi(uu[e]), wt[e * 2 + 1], qf[e * 2 + 1]);
            }
        }
    }
    float qs = 0.f;
    #pragma unroll
    for (int e = 0; e < 8; ++e) qs = fmaf(qf[e], qf[e], qs);
    qs += __shfl_xor(qs, 16);
    qs += __shfl_xor(qs, 32);
    float qinv = 1.0f / fmaxf(sqrtf(qs), 1e-12f);
    short8 bq;
    #pragma unroll
    for (int e = 0; e < 8; ++e) bq[e] = (short)f2bf(qf[e] * qinv);
    __syncthreads();

    // ---- QK^T: S^T[nbr][px], 13 n-tiles of 16 nbrs ----
    floatx4 acc[13];
    #pragma unroll
    for (int mt = 0; mt < 13; ++mt) {
        short8 ak = *(const short8*)&Ks[(mt * 16 + lm) * 40 + lq * 8];
        floatx4 z = {0.f, 0.f, 0.f, 0.f};
        acc[mt] = __builtin_amdgcn_mfma_f32_16x16x32_bf16(ak, bq, z, 0, 0, 0);
    }
    __syncthreads();                        // Ks dead; Ps may overwrite

    // ---- mask + bias + softmax ----
    const int si = min(max(i - 3, 0), 57), sj = min(max(j - 3, 0), 57);
    const int vloi = si - r0, vloj = sj - c0;
    const int oi = r0 - i + 6, oj = c0 - j + 6;
    const float th = temp[head];
    float mx = -1e30f;
    #pragma unroll
    for (int mt = 0; mt < 13; ++mt) {
        int nb0 = mt * 16 + lq * 4;
        int rh0 = (nb0 * 2341) >> 15;
        int ch0 = nb0 - rh0 * 14;
        #pragma unroll
        for (int r = 0; r < 4; ++r) {
            int ch = ch0 + r, rh = rh0;
            if (ch >= 14) { ch -= 14; rh += 1; }
            int bidx = (rh + oi) * 13 + (ch + oj);
            float bias = rpbs[max(0, min(168, bidx))];
            bool valid = ((unsigned)(rh - vloi) <= 6u) && ((unsigned)(ch - vloj) <= 6u);
            float s = (acc[mt][r] + bias) * th;
            s = valid ? s : -1e30f;
            acc[mt][r] = s;
            mx = fmaxf(mx, s);
        }
    }
    mx = fmaxf(mx, __shfl_xor(mx, 16));
    mx = fmaxf(mx, __shfl_xor(mx, 32));
    float ssum = 0.f;
    #pragma unroll
    for (int mt = 0; mt < 13; ++mt)
        #pragma unroll
        for (int r = 0; r < 4; ++r) {
            float e = __expf(acc[mt][r] - mx);
            acc[mt][r] = e;
            ssum += e;
        }
    ssum += __shfl_xor(ssum, 16);
    ssum += __shfl_xor(ssum, 32);
    const float rs = 1.0f / ssum;

    if (lane < 32) {                       // zero Ps pad cols 208..223
        uint4 z4 = {0u, 0u, 0u, 0u};
        *(uint4*)&Ps[(w * 16 + (lane >> 1)) * 232 + 208 + (lane & 1) * 8] = z4;
    }
    #pragma unroll
    for (int mt = 0; mt < 13; ++mt) {
        unsigned lo = (unsigned)f2h(acc[mt][0] * rs) | ((unsigned)f2h(acc[mt][1] * rs) << 16);
        unsigned hi = (unsigned)f2h(acc[mt][2] * rs) | ((unsigned)f2h(acc[mt][3] * rs) << 16);
        *(uint2*)&Ps[px * 232 + mt * 16 + lq * 4] = make_uint2(lo, hi);
    }
    __syncthreads();

    // ---- PV: O[px][d] = P x V^T ----
    floatx4 oacc[2] = {};
    #pragma unroll
    for (int ks = 0; ks < 7; ++ks) {
        half8 ap = *(const half8*)&Ps[(w * 16 + lm) * 232 + ks * 32 + lq * 8];
        #pragma unroll
        for (int n2 = 0; n2 < 2; ++n2) {
            half8 bv = *(const half8*)&Vts[(n2 * 16 + lm) * 232 + ks * 32 + lq * 8];
            oacc[n2] = __builtin_amdgcn_mfma_f32_16x16x32_f16(ap, bv, oacc[n2], 0, 0, 0);
        }
    }
    #pragma unroll
    for (int n2 = 0; n2 < 2; ++n2)
        #pragma unroll
        for (int r = 0; r < 4; ++r) {
            int p2 = w * 16 + lq * 4 + r;
            int i2 = i0 + (p2 >> 3), j2 = j0 + (p2 & 7);
            attnO[((size_t)((b << 12) + (i2 << 6) + j2)) * 192 + head * 32 + n2 * 16 + lm]
                = f2bf(oacc[n2][r]);
        }
}

// ---------------------------------------------------------------------------
// K4: proj 1x1 as bf16 MFMA GEMM. M=8192 N=192 K=192. (unchanged)
// ---------------------------------------------------------------------------
__global__ __launch_bounds__(256) void k_gp(const unsigned short* __restrict__ Ain,
    const float* __restrict__ Wp, const float* __restrict__ bp,
    float* __restrict__ out)
{
    __shared__ __align__(16) unsigned short As[64 * 200];
    __shared__ __align__(16) unsigned short Bs[64 * 200];
    const int t = threadIdx.x;
    const int m0 = blockIdx.x * 64;
    const int n0 = blockIdx.y * 64;
    #pragma unroll
    for (int pass = 0; pass < 6; ++pass) {
        int idx = pass * 256 + t;
        int m = idx / 24, c16 = idx % 24;
        *(uint4*)&As[m * 200 + c16 * 8] = *(const uint4*)&Ain[(size_t)(m0 + m) * 192 + c16 * 8];
    }
    #pragma unroll
    for (int pass = 0; pass < 12; ++pass) {
        int idx = pass * 256 + t;
        int row = idx / 48, ch = idx - row * 48;
        float4 wv = *(const float4*)&Wp[(size_t)(n0 + row) * 192 + ch * 4];
        *(uint2*)&Bs[row * 200 + ch * 4] =
            make_uint2(f2bf2(wv.x, wv.y), f2bf2(wv.z, wv.w));
    }
    __syncthreads();
    const int w = t >> 6, lane = t & 63;
    const int lm = lane & 15, lq = lane >> 4;
    floatx4 acc[4] = {};
    #pragma unroll
    for (int ks = 0; ks < 6; ++ks) {
        short8 bf = *(const short8*)&Bs[(w * 16 + lm) * 200 + ks * 32 + lq * 8];
        #pragma unroll
        for (int mt = 0; mt < 4; ++mt) {
            short8 af = *(const short8*)&As[(mt * 16 + lm) * 200 + ks * 32 + lq * 8];
            acc[mt] = __builtin_amdgcn_mfma_f32_16x16x32_bf16(af, bf, acc[mt], 0, 0, 0);
        }
    }
    __syncthreads();
    float* fs = (float*)As;                 // [n][m] stride 68
    const float bias = bp[n0 + w * 16 + lm];
    #pragma unroll
    for (int mt = 0; mt < 4; ++mt)
        #pragma unroll
        for (int r = 0; r < 4; ++r)
            fs[(w * 16 + lm) * 68 + mt * 16 + lq * 4 + r] = acc[mt][r] + bias;
    __syncthreads();
    const int b = m0 >> 12, px0 = m0 & 4095;
    #pragma unroll
    for (int pass = 0; pass < 4; ++pass) {
        int idx = pass * 256 + t;           // 64 n x 16 m-quads
        int n = idx >> 4, m4 = idx & 15;
        float4 val = *(const float4*)&fs[n * 68 + m4 * 4];
        *(float4*)&out[((size_t)(b * 192 + n0 + n) << 12) + px0 + m4 * 4] = val;
    }
}

extern "C" void kernel_launch(void* const* d_in, const int* in_sizes, int n_in,
                              void* d_out, int out_size, void* d_ws, size_t ws_size,
                              hipStream_t stream) {
    const float* x    = (const float*)d_in[0];
    const float* W1   = (const float*)d_in[1];
    const float* b1   = (const float*)d_in[2];
    const float* W2   = (const float*)d_in[3];
    const float* b2   = (const float*)d_in[4];
    const float* temp = (const float*)d_in[5];
    const float* rpb  = (const float*)d_in[6];
    const float* Wp   = (const float*)d_in[7];
    const float* bp   = (const float*)d_in[8];
    float* out = (float*)d_out;

    char* ws = (char*)d_ws;
    unsigned short* qkv1b = (unsigned short*)(ws);
    unsigned short* attnO = (unsigned short*)(ws + 9437184);
    unsigned short* xT    = (unsigned short*)(ws + 12582912);

    k_tr  <<<dim3(128), 256, 0, stream>>>(x, xT);
    k_gq  <<<dim3(128, 9), 256, 0, stream>>>(xT, W1, b1, qkv1b);
    k_attn<<<dim3(64, 6, 2), 256, 0, stream>>>(qkv1b, W2, b2, temp, rpb, attnO);
    k_gp  <<<dim3(128, 3), 256, 0, stream>>>(attnO, Wp, bp, out);
}

// Round 8
// 113.568 us; speedup vs baseline: 2.4028x; 1.0258x over previous
//
#include <hip/hip_runtime.h>
#include <math.h>

#define HW 4096

typedef __attribute__((ext_vector_type(8))) short short8;
typedef __attribute__((ext_vector_type(8))) _Float16 half8;
typedef __attribute__((ext_vector_type(4))) float floatx4;

// ---- bf16 helpers (round-to-nearest-even) ----
__device__ inline float bflo(unsigned u) { return __uint_as_float(u << 16); }
__device__ inline float bfhi(unsigned u) { return __uint_as_float(u & 0xffff0000u); }
__device__ inline unsigned short f2bf(float x) {
    unsigned u = __float_as_uint(x);
    return (unsigned short)((u + 0x7fffu + ((u >> 16) & 1u)) >> 16);
}
__device__ inline unsigned f2bf2(float lo, float hi) {
    unsigned a = __float_as_uint(lo), b = __float_as_uint(hi);
    a = (a + 0x7fffu + ((a >> 16) & 1u)) >> 16;
    b = (b + 0x7fffu + ((b >> 16) & 1u)) & 0xffff0000u;
    return a | b;
}
__device__ inline unsigned short f2h(float x) {
    _Float16 h = (_Float16)x;
    return __builtin_bit_cast(unsigned short, h);
}

// ws layout (bytes):
//   qkv1b @ 0        : 2*18*4096*32*2 = 9437184  bf16 [b][g][px][32] (pre-dw)
//   qkv2b @ 9437184  : 9437184                   bf16 (post-dw)
//   attnO @ 18874368 : 2*4096*192*2 = 3145728    bf16 [b*px][c]

// ---------------------------------------------------------------------------
// K1: QKV 1x1 conv as bf16 MFMA GEMM, M=8192(px) N=576(oc) K=192.
// Transpose+convert fused into staging:
//   A: x fp32 [c][px] -> As[px][c] bf16 (wave-row coalesced b32 loads,
//      reg-pack 4c -> one b64 LDS write; stride 200 keeps frag reads b128).
//   B: W1 fp32 [oc][c] -> Bs bf16 (float4 load + packed convert).
// out bf16 [b][g][px][32], bias fused in epilogue.
// ---------------------------------------------------------------------------
__global__ __launch_bounds__(256) void k_gq(const float* __restrict__ x,
    const float* __restrict__ W1, const float* __restrict__ b1,
    unsigned short* __restrict__ qkv)
{
    __shared__ __align__(16) unsigned short As[64 * 200];
    __shared__ __align__(16) unsigned short Bs[64 * 200];
    const int t = threadIdx.x;
    const int m0 = blockIdx.x * 64;
    const int n0 = blockIdx.y * 64;
    const int w = t >> 6, lane = t & 63;
    const int b = m0 >> 12, px0 = m0 & 4095;
    // ---- A: transpose-convert 64px x 192c ----
    {
        const float* xb = x + ((size_t)(b * 192) << 12) + px0 + lane;
        const int cb = w * 48;
        #pragma unroll
        for (int r4 = 0; r4 < 12; ++r4) {
            float v0 = xb[(size_t)(cb + r4 * 4 + 0) << 12];
            float v1 = xb[(size_t)(cb + r4 * 4 + 1) << 12];
            float v2 = xb[(size_t)(cb + r4 * 4 + 2) << 12];
            float v3 = xb[(size_t)(cb + r4 * 4 + 3) << 12];
            *(uint2*)&As[lane * 200 + cb + r4 * 4] =
                make_uint2(f2bf2(v0, v1), f2bf2(v2, v3));
        }
    }
    // ---- B: convert W1 slice [n0..n0+63][192] ----
    #pragma unroll
    for (int pass = 0; pass < 12; ++pass) {
        int idx = pass * 256 + t;
        int row = idx / 48, ch = idx - row * 48;
        float4 wv = *(const float4*)&W1[(size_t)(n0 + row) * 192 + ch * 4];
        *(uint2*)&Bs[row * 200 + ch * 4] =
            make_uint2(f2bf2(wv.x, wv.y), f2bf2(wv.z, wv.w));
    }
    __syncthreads();
    const int lm = lane & 15, lq = lane >> 4;
    floatx4 acc[4] = {};
    #pragma unroll
    for (int ks = 0; ks < 6; ++ks) {
        short8 bf = *(const short8*)&Bs[(w * 16 + lm) * 200 + ks * 32 + lq * 8];
        #pragma unroll
        for (int mt = 0; mt < 4; ++mt) {
            short8 af = *(const short8*)&As[(mt * 16 + lm) * 200 + ks * 32 + lq * 8];
            acc[mt] = __builtin_amdgcn_mfma_f32_16x16x32_bf16(af, bf, acc[mt], 0, 0, 0);
        }
    }
    __syncthreads();
    const float bias = b1[n0 + w * 16 + lm];
    #pragma unroll
    for (int mt = 0; mt < 4; ++mt)
        #pragma unroll
        for (int r = 0; r < 4; ++r)
            As[(mt * 16 + lq * 4 + r) * 72 + w * 16 + lm] = f2bf(acc[mt][r] + bias);
    __syncthreads();
    #pragma unroll
    for (int pass = 0; pass < 2; ++pass) {
        int idx = pass * 256 + t;           // 64 m x 8 n-groups
        int m = idx >> 3, n8 = idx & 7;
        uint4 val = *(const uint4*)&As[m * 72 + n8 * 8];
        int oc = n0 + n8 * 8;
        int g = oc >> 5, d = oc & 31;
        *(uint4*)&qkv[((((size_t)(b * 18 + g) << 12) + px0 + m) << 5) + d] = val;
    }
}

// ---------------------------------------------------------------------------
// K2: depthwise 3x3, bf16 in/out, fp32 math, weights staged in LDS.
// ---------------------------------------------------------------------------
__global__ __launch_bounds__(256) void k_dw(const unsigned short* __restrict__ in,
    const float* __restrict__ W2, const float* __restrict__ b2,
    unsigned short* __restrict__ outq)
{
    __shared__ float wsm[288];
    __shared__ float bsm[32];
    const int t = threadIdx.x;
    const int bg = blockIdx.y;
    const int g = (bg >= 18) ? bg - 18 : bg;
    const int cbase = (g / 6) * 192 + (g % 6) * 32;
    for (int idx = t; idx < 288; idx += 256)
        wsm[idx] = W2[(cbase + (idx & 31)) * 9 + (idx >> 5)];
    if (t < 32) bsm[t] = b2[cbase + t];
    __syncthreads();
    const int px = (blockIdx.x << 6) + (t >> 2);
    const int d8 = t & 3;
    const int i = px >> 6, j = px & 63;
    const unsigned short* base = in + ((size_t)bg << 17);
    float acc[8];
    #pragma unroll
    for (int e = 0; e < 8; ++e) acc[e] = bsm[d8 * 8 + e];
    #pragma unroll
    for (int di = -1; di <= 1; ++di) {
        int ii = i + di;
        if (ii < 0 || ii > 63) continue;
        #pragma unroll
        for (int dj = -1; dj <= 1; ++dj) {
            int jj = j + dj;
            if (jj < 0 || jj > 63) continue;
            int tap = (di + 1) * 3 + dj + 1;
            uint4 u = *(const uint4*)(base + ((((ii << 6) + jj) << 5) + d8 * 8));
            const float* wt = &wsm[tap * 32 + d8 * 8];
            acc[0] = fmaf(bflo(u.x), wt[0], acc[0]);
            acc[1] = fmaf(bfhi(u.x), wt[1], acc[1]);
            acc[2] = fmaf(bflo(u.y), wt[2], acc[2]);
            acc[3] = fmaf(bfhi(u.y), wt[3], acc[3]);
            acc[4] = fmaf(bflo(u.z), wt[4], acc[4]);
            acc[5] = fmaf(bfhi(u.z), wt[5], acc[5]);
            acc[6] = fmaf(bflo(u.w), wt[6], acc[6]);
            acc[7] = fmaf(bfhi(u.w), wt[7], acc[7]);
        }
    }
    uint4 o;
    o.x = f2bf2(acc[0], acc[1]); o.y = f2bf2(acc[2], acc[3]);
    o.z = f2bf2(acc[4], acc[5]); o.w = f2bf2(acc[6], acc[7]);
    *(uint4*)(outq + ((size_t)bg << 17) + ((size_t)px << 5) + d8 * 8) = o;
}

// ---------------------------------------------------------------------------
// K3: MFMA neighborhood attention (R5 structure, unfused dw).
// Block 256 = (b, head, 8x8 tile), 4 waves. S^T = K-hat x q-hat^T (mfma bf16),
// mask+bias+softmax in regs, P f16 -> LDS (aliases Ks), PV via mfma f16.
// ---------------------------------------------------------------------------
__global__ __launch_bounds__(256) void k_attn(const unsigned short* __restrict__ qkv,
    const float* __restrict__ temp, const float* __restrict__ rpb,
    unsigned short* __restrict__ attnO)
{
    __shared__ __align__(16) char lds[45224];
    unsigned short* Ks  = (unsigned short*)lds;            // [208][40] bf16
    unsigned short* Ps  = (unsigned short*)lds;            // [64][232] f16 (alias)
    unsigned short* Vts = (unsigned short*)(lds + 29696);  // [32][232] f16
    float* rpbs = (float*)(lds + 44544);                   // [169]

    const int t = threadIdx.x;
    const int ti = blockIdx.x >> 3, tj = blockIdx.x & 7;
    const int head = blockIdx.y, b = blockIdx.z;
    const int i0 = ti * 8, j0 = tj * 8;
    const int r0 = min(max(i0 - 3, 0), 50), c0 = min(max(j0 - 3, 0), 50);
    const unsigned short* qpl = qkv + ((size_t)(b * 18 + head) << 17);
    const unsigned short* kpl = qkv + ((size_t)(b * 18 + 6 + head) << 17);
    const unsigned short* vpl = qkv + ((size_t)(b * 18 + 12 + head) << 17);

    // ---- stage K-hat (bf16, l2-normalized) and V^T (f16) ----
    if (t < 196) {
        int r = (t * 2341) >> 15, cc = t - r * 14;
        int pix = ((r0 + r) << 6) + (c0 + cc);
        const uint4* kg = (const uint4*)(kpl + (pix << 5));
        const uint4* vg = (const uint4*)(vpl + (pix << 5));
        float kf[32];
        float ss = 0.f;
        #pragma unroll
        for (int q = 0; q < 4; ++q) {
            uint4 ku = kg[q];
            unsigned uu[4] = {ku.x, ku.y, ku.z, ku.w};
            #pragma unroll
            for (int e = 0; e < 4; ++e) {
                float lo = bflo(uu[e]), hi = bfhi(uu[e]);
                kf[q * 8 + e * 2] = lo; kf[q * 8 + e * 2 + 1] = hi;
                ss = fmaf(lo, lo, fmaf(hi, hi, ss));
            }
        }
        float rinv = 1.0f / fmaxf(sqrtf(ss), 1e-12f);
        #pragma unroll
        for (int q = 0; q < 4; ++q) {
            uint4 p;
            p.x = f2bf2(kf[q * 8 + 0] * rinv, kf[q * 8 + 1] * rinv);
            p.y = f2bf2(kf[q * 8 + 2] * rinv, kf[q * 8 + 3] * rinv);
            p.z = f2bf2(kf[q * 8 + 4] * rinv, kf[q * 8 + 5] * rinv);
            p.w = f2bf2(kf[q * 8 + 6] * rinv, kf[q * 8 + 7] * rinv);
            *(uint4*)&Ks[t * 40 + q * 8] = p;
        }
        #pragma unroll
        for (int q = 0; q < 4; ++q) {
            uint4 vu = vg[q];
            unsigned uu[4] = {vu.x, vu.y, vu.z, vu.w};
            #pragma unroll
            for (int e = 0; e < 4; ++e) {
                Vts[(q * 8 + e * 2) * 232 + t]     = f2h(bflo(uu[e]));
                Vts[(q * 8 + e * 2 + 1) * 232 + t] = f2h(bfhi(uu[e]));
            }
        }
    }
    // zero V^T cols 196..223 (PV pad region must be 0)
    for (int idx = t; idx < 448; idx += 256) {
        int row = (idx * 2341) >> 15;
        int c = idx - row * 14;
        ((unsigned*)(Vts + row * 232))[98 + c] = 0u;
    }
    if (t < 169) rpbs[t] = rpb[head * 169 + t];

    // ---- q-hat fragment in registers ----
    const int w = t >> 6, lane = t & 63;
    const int lm = lane & 15, lq = lane >> 4;
    const int px = w * 16 + lm;
    const int i = i0 + (px >> 3), j = j0 + (px & 7);
    uint4 qu = *(const uint4*)(qpl + ((((i << 6) + j) << 5) + lq * 8));
    float qf[8];
    qf[0] = bflo(qu.x); qf[1] = bfhi(qu.x);
    qf[2] = bflo(qu.y); qf[3] = bfhi(qu.y);
    qf[4] = bflo(qu.z); qf[5] = bfhi(qu.z);
    qf[6] = bflo(qu.w); qf[7] = bfhi(qu.w);
    float qs = 0.f;
    #pragma unroll
    for (int e = 0; e < 8; ++e) qs = fmaf(qf[e], qf[e], qs);
    qs += __shfl_xor(qs, 16);
    qs += __shfl_xor(qs, 32);
    float qinv = 1.0f / fmaxf(sqrtf(qs), 1e-12f);
    short8 bq;
    #pragma unroll
    for (int e = 0; e < 8; ++e) bq[e] = (short)f2bf(qf[e] * qinv);
    __syncthreads();

    // ---- QK^T: S^T[nbr][px], 13 n-tiles of 16 nbrs ----
    floatx4 acc[13];
    #pragma unroll
    for (int mt = 0; mt < 13; ++mt) {
        short8 ak = *(const short8*)&Ks[(mt * 16 + lm) * 40 + lq * 8];
        floatx4 z = {0.f, 0.f, 0.f, 0.f};
        acc[mt] = __builtin_amdgcn_mfma_f32_16x16x32_bf16(ak, bq, z, 0, 0, 0);
    }
    __syncthreads();                        // Ks dead; Ps may overwrite

    // ---- mask + bias + softmax ----
    const int si = min(max(i - 3, 0), 57), sj = min(max(j - 3, 0), 57);
    const int vloi = si - r0, vloj = sj - c0;
    const int oi = r0 - i + 6, oj = c0 - j + 6;
    const float th = temp[head];
    float mx = -1e30f;
    #pragma unroll
    for (int mt = 0; mt < 13; ++mt) {
        int nb0 = mt * 16 + lq * 4;
        int rh0 = (nb0 * 2341) >> 15;
        int ch0 = nb0 - rh0 * 14;
        #pragma unroll
        for (int r = 0; r < 4; ++r) {
            int ch = ch0 + r, rh = rh0;
            if (ch >= 14) { ch -= 14; rh += 1; }
            int bidx = (rh + oi) * 13 + (ch + oj);
            float bias = rpbs[max(0, min(168, bidx))];
            bool valid = ((unsigned)(rh - vloi) <= 6u) && ((unsigned)(ch - vloj) <= 6u);
            float s = (acc[mt][r] + bias) * th;
            s = valid ? s : -1e30f;
            acc[mt][r] = s;
            mx = fmaxf(mx, s);
        }
    }
    mx = fmaxf(mx, __shfl_xor(mx, 16));
    mx = fmaxf(mx, __shfl_xor(mx, 32));
    float ssum = 0.f;
    #pragma unroll
    for (int mt = 0; mt < 13; ++mt)
        #pragma unroll
        for (int r = 0; r < 4; ++r) {
            float e = __expf(acc[mt][r] - mx);
            acc[mt][r] = e;
            ssum += e;
        }
    ssum += __shfl_xor(ssum, 16);
    ssum += __shfl_xor(ssum, 32);
    const float rs = 1.0f / ssum;

    if (lane < 32) {                       // zero Ps pad cols 208..223
        uint4 z4 = {0u, 0u, 0u, 0u};
        *(uint4*)&Ps[(w * 16 + (lane >> 1)) * 232 + 208 + (lane & 1) * 8] = z4;
    }
    #pragma unroll
    for (int mt = 0; mt < 13; ++mt) {
        unsigned lo = (unsigned)f2h(acc[mt][0] * rs) | ((unsigned)f2h(acc[mt][1] * rs) << 16);
        unsigned hi = (unsigned)f2h(acc[mt][2] * rs) | ((unsigned)f2h(acc[mt][3] * rs) << 16);
        *(uint2*)&Ps[px * 232 + mt * 16 + lq * 4] = make_uint2(lo, hi);
    }
    __syncthreads();

    // ---- PV: O[px][d] = P x V^T ----
    floatx4 oacc[2] = {};
    #pragma unroll
    for (int ks = 0; ks < 7; ++ks) {
        half8 ap = *(const half8*)&Ps[(w * 16 + lm) * 232 + ks * 32 + lq * 8];
        #pragma unroll
        for (int n2 = 0; n2 < 2; ++n2) {
            half8 bv = *(const half8*)&Vts[(n2 * 16 + lm) * 232 + ks * 32 + lq * 8];
            oacc[n2] = __builtin_amdgcn_mfma_f32_16x16x32_f16(ap, bv, oacc[n2], 0, 0, 0);
        }
    }
    #pragma unroll
    for (int n2 = 0; n2 < 2; ++n2)
        #pragma unroll
        for (int r = 0; r < 4; ++r) {
            int p2 = w * 16 + lq * 4 + r;
            int i2 = i0 + (p2 >> 3), j2 = j0 + (p2 & 7);
            attnO[((size_t)((b << 12) + (i2 << 6) + j2)) * 192 + head * 32 + n2 * 16 + lm]
                = f2bf(oacc[n2][r]);
        }
}

// ---------------------------------------------------------------------------
// K4: proj 1x1 as bf16 MFMA GEMM. M=8192 N=192 K=192. Wp converted fp32->bf16
// in staging. fp32 NCHW out + bias.
// ---------------------------------------------------------------------------
__global__ __launch_bounds__(256) void k_gp(const unsigned short* __restrict__ Ain,
    const float* __restrict__ Wp, const float* __restrict__ bp,
    float* __restrict__ out)
{
    __shared__ __align__(16) unsigned short As[64 * 200];
    __shared__ __align__(16) unsigned short Bs[64 * 200];
    const int t = threadIdx.x;
    const int m0 = blockIdx.x * 64;
    const int n0 = blockIdx.y * 64;
    #pragma unroll
    for (int pass = 0; pass < 6; ++pass) {
        int idx = pass * 256 + t;
        int m = idx / 24, c16 = idx % 24;
        *(uint4*)&As[m * 200 + c16 * 8] = *(const uint4*)&Ain[(size_t)(m0 + m) * 192 + c16 * 8];
    }
    #pragma unroll
    for (int pass = 0; pass < 12; ++pass) {
        int idx = pass * 256 + t;
        int row = idx / 48, ch = idx - row * 48;
        float4 wv = *(const float4*)&Wp[(size_t)(n0 + row) * 192 + ch * 4];
        *(uint2*)&Bs[row * 200 + ch * 4] =
            make_uint2(f2bf2(wv.x, wv.y), f2bf2(wv.z, wv.w));
    }
    __syncthreads();
    const int w = t >> 6, lane = t & 63;
    const int lm = lane & 15, lq = lane >> 4;
    floatx4 acc[4] = {};
    #pragma unroll
    for (int ks = 0; ks < 6; ++ks) {
        short8 bf = *(const short8*)&Bs[(w * 16 + lm) * 200 + ks * 32 + lq * 8];
        #pragma unroll
        for (int mt = 0; mt < 4; ++mt) {
            short8 af = *(const short8*)&As[(mt * 16 + lm) * 200 + ks * 32 + lq * 8];
            acc[mt] = __builtin_amdgcn_mfma_f32_16x16x32_bf16(af, bf, acc[mt], 0, 0, 0);
        }
    }
    __syncthreads();
    float* fs = (float*)As;                 // [n][m] stride 68
    const float bias = bp[n0 + w * 16 + lm];
    #pragma unroll
    for (int mt = 0; mt < 4; ++mt)
        #pragma unroll
        for (int r = 0; r < 4; ++r)
            fs[(w * 16 + lm) * 68 + mt * 16 + lq * 4 + r] = acc[mt][r] + bias;
    __syncthreads();
    const int b = m0 >> 12, px0 = m0 & 4095;
    #pragma unroll
    for (int pass = 0; pass < 4; ++pass) {
        int idx = pass * 256 + t;           // 64 n x 16 m-quads
        int n = idx >> 4, m4 = idx & 15;
        float4 val = *(const float4*)&fs[n * 68 + m4 * 4];
        *(float4*)&out[((size_t)(b * 192 + n0 + n) << 12) + px0 + m4 * 4] = val;
    }
}

extern "C" void kernel_launch(void* const* d_in, const int* in_sizes, int n_in,
                              void* d_out, int out_size, void* d_ws, size_t ws_size,
                              hipStream_t stream) {
    const float* x    = (const float*)d_in[0];
    const float* W1   = (const float*)d_in[1];
    const float* b1   = (const float*)d_in[2];
    const float* W2   = (const float*)d_in[3];
    const float* b2   = (const float*)d_in[4];
    const float* temp = (const float*)d_in[5];
    const float* rpb  = (const float*)d_in[6];
    const float* Wp   = (const float*)d_in[7];
    const float* bp   = (const float*)d_in[8];
    float* out = (float*)d_out;

    char* ws = (char*)d_ws;
    unsigned short* qkv1b = (unsigned short*)(ws);
    unsigned short* qkv2b = (unsigned short*)(ws + 9437184);
    unsigned short* attnO = (unsigned short*)(ws + 18874368);

    k_gq  <<<dim3(128, 9), 256, 0, stream>>>(x, W1, b1, qkv1b);
    k_dw  <<<dim3(64, 36), 256, 0, stream>>>(qkv1b, W2, b2, qkv2b);
    k_attn<<<dim3(64, 6, 2), 256, 0, stream>>>(qkv2b, temp, rpb, attnO);
    k_gp  <<<dim3(128, 3), 256, 0, stream>>>(attnO, Wp, bp, out);
}